// Round 3
// baseline (64.653 us; speedup 1.0000x reference)
//
#include <hip/hip_runtime.h>

#define BD 4
#define CD 3
#define HD 512
#define WD 512
#define NPAT 4096
#define NP (BD * NPAT)            // 16384 patches
#define NBAND 16                  // h >> 5 -> 16 bands of 32 rows
#define SH 5
#define KEYS (BD * NBAND)         // 64 buckets
#define PLANE (HD * WD)
#define TOTAL_ELEMS (4.0 * 3.0 * 4096.0 * 256.0)   // 12,582,912

typedef float f4 __attribute__((ext_vector_type(4), aligned(4)));

// ---------------- kernel 1: deterministic counting sort by (b, h-band) ----
__global__ __launch_bounds__(256) void build_order(
    const int* __restrict__ coords, int* __restrict__ order)
{
    __shared__ unsigned short cnt[256][KEYS];   // 32 KB
    __shared__ unsigned char  keys[NP];         // 16 KB
    __shared__ unsigned int   base[KEYS];

    const int t = threadIdx.x;
    #pragma unroll
    for (int k = 0; k < KEYS; ++k) cnt[t][k] = 0;
    __syncthreads();

    const int p0 = t * 64;                      // this thread's 64 patches
    for (int i = 0; i < 64; ++i) {
        const int p = p0 + i;
        const int h = coords[p * 2];
        const int key = (p >> 12) * NBAND + (h >> SH);
        keys[p] = (unsigned char)key;
        cnt[t][key]++;
    }
    __syncthreads();

    // per-key exclusive prefix across the 256 thread-chunks
    if (t < KEYS) {
        unsigned int run = 0;
        for (int tt = 0; tt < 256; ++tt) {
            const unsigned int v = cnt[tt][t];
            cnt[tt][t] = (unsigned short)run;
            run += v;
        }
        base[t] = run;                          // bucket totals (for now)
    }
    __syncthreads();
    if (t == 0) {
        unsigned int run = 0;
        for (int k = 0; k < KEYS; ++k) {
            const unsigned int v = base[k];
            base[k] = run;
            run += v;
        }
    }
    __syncthreads();

    // stable scatter: thread t walks its chunk in order, cursor in cnt[t][key]
    for (int i = 0; i < 64; ++i) {
        const int p = p0 + i;
        const int key = keys[p];
        const unsigned int pos = base[key] + cnt[t][key];
        cnt[t][key]++;
        order[pos] = p;
    }
}

// ---------------- kernel 2: per-patch loss, processed in sorted order ----
__global__ __launch_bounds__(256) void patch_stage1(
    const float* __restrict__ fuse,
    const float* __restrict__ img1,
    const float* __restrict__ img2,
    const int*   __restrict__ coords,
    const int*   __restrict__ order,
    float*       __restrict__ partials)
{
    const int lane = threadIdx.x & 63;
    const int wave = threadIdx.x >> 6;
    const int slot = blockIdx.x * 4 + wave;     // 0..16383 (sorted order)
    const int p = order[slot];
    const int b = p >> 12;

    const int h = coords[p * 2];
    const int w = coords[p * 2 + 1];

    // lane covers 4 contiguous cols: row = lane>>2, col = (lane&3)*4
    const size_t pbase = ((size_t)(b * CD) * HD + h) * WD + w
                       + (size_t)(lane >> 2) * WD + (size_t)((lane & 3) * 4);

    // Issue all 9 16B loads before any dependent compute.
    f4 vf[3], v1[3], v2[3];
    #pragma unroll
    for (int c = 0; c < CD; ++c) {
        const size_t idx = pbase + (size_t)c * PLANE;
        vf[c] = *(const f4*)(fuse + idx);
        v1[c] = *(const f4*)(img1 + idx);
        v2[c] = *(const f4*)(img2 + idx);
    }

    float s1[3], q1[3], s2[3], q2[3];
    #pragma unroll
    for (int c = 0; c < CD; ++c) {
        s1[c] = v1[c].x + v1[c].y + v1[c].z + v1[c].w;
        q1[c] = v1[c].x * v1[c].x + v1[c].y * v1[c].y
              + v1[c].z * v1[c].z + v1[c].w * v1[c].w;
        s2[c] = v2[c].x + v2[c].y + v2[c].z + v2[c].w;
        q2[c] = v2[c].x * v2[c].x + v2[c].y * v2[c].y
              + v2[c].z * v2[c].z + v2[c].w * v2[c].w;
    }

    // 12 independent butterfly chains, interleaved
    #pragma unroll
    for (int off = 32; off >= 1; off >>= 1) {
        #pragma unroll
        for (int c = 0; c < CD; ++c) {
            s1[c] += __shfl_xor(s1[c], off, 64);
            q1[c] += __shfl_xor(q1[c], off, 64);
            s2[c] += __shfl_xor(s2[c], off, 64);
            q2[c] += __shfl_xor(q2[c], off, 64);
        }
    }

    float acc = 0.f;
    const float inv = 1.f / 256.f;
    #pragma unroll
    for (int c = 0; c < CD; ++c) {
        const float mu1 = s1[c] * inv;
        const float mu2 = s2[c] * inv;
        const float sd1 = sqrtf(fmaxf(q1[c] * inv - mu1 * mu1, 0.f));
        const float sd2 = sqrtf(fmaxf(q2[c] * inv - mu2 * mu2, 0.f));
        const float denom = sd1 + sd2 + 1e-6f;
        const float w1 = sd1 / denom;
        const float w2 = sd2 / denom;
        acc += fabsf(vf[c].x - (w1 * v1[c].x + w2 * v2[c].x))
             + fabsf(vf[c].y - (w1 * v1[c].y + w2 * v2[c].y))
             + fabsf(vf[c].z - (w1 * v1[c].z + w2 * v2[c].z))
             + fabsf(vf[c].w - (w1 * v1[c].w + w2 * v2[c].w));
    }

    #pragma unroll
    for (int off = 32; off >= 1; off >>= 1)
        acc += __shfl_xor(acc, off, 64);

    __shared__ float part[4];
    if (lane == 0) part[wave] = acc;
    __syncthreads();
    if (threadIdx.x == 0)
        partials[blockIdx.x] = part[0] + part[1] + part[2] + part[3];
}

// ---------------- kernel 3: final reduction ----
__global__ __launch_bounds__(256) void patch_stage2(
    const float* __restrict__ partials, float* __restrict__ out)
{
    const int NB = NP / 4;                      // 4096 partials
    float s = 0.f;
    for (int i = threadIdx.x; i < NB; i += 256)
        s += partials[i];

    #pragma unroll
    for (int off = 32; off >= 1; off >>= 1)
        s += __shfl_xor(s, off, 64);

    __shared__ float part[4];
    const int lane = threadIdx.x & 63;
    const int wave = threadIdx.x >> 6;
    if (lane == 0) part[wave] = s;
    __syncthreads();
    if (threadIdx.x == 0)
        out[0] = (part[0] + part[1] + part[2] + part[3]) * (float)(1.0 / TOTAL_ELEMS);
}

extern "C" void kernel_launch(void* const* d_in, const int* in_sizes, int n_in,
                              void* d_out, int out_size, void* d_ws, size_t ws_size,
                              hipStream_t stream) {
    const float* fuse   = (const float*)d_in[0];
    const float* img1   = (const float*)d_in[1];
    const float* img2   = (const float*)d_in[2];
    const int*   coords = (const int*)d_in[3];
    float* out = (float*)d_out;

    int*   order    = (int*)d_ws;                       // 64 KB
    float* partials = (float*)((char*)d_ws + NP * 4);   // 16 KB

    build_order<<<1, 256, 0, stream>>>(coords, order);
    patch_stage1<<<NP / 4, 256, 0, stream>>>(fuse, img1, img2, coords, order, partials);
    patch_stage2<<<1, 256, 0, stream>>>(partials, out);
}

// Round 4
// 34.117 us; speedup vs baseline: 1.8950x; 1.8950x over previous
//
#include <hip/hip_runtime.h>

#define BD 4
#define CD 3
#define HD 512
#define WD 512
#define NPAT 4096
#define NP (BD * NPAT)            // 16384 patches
#define PLANE (HD * WD)
#define NBLK (NP / 4)             // 4096 stage1 blocks (4 patches each)
#define TOTAL_ELEMS (4.0 * 3.0 * 4096.0 * 256.0)   // 12,582,912

typedef float f4 __attribute__((ext_vector_type(4), aligned(4)));

// ---- kernel 1: per-batch counting sort by 32-row h-band; packs (b,h,w) ----
// grid = 4 blocks (one per batch), 256 threads each.
__global__ __launch_bounds__(256) void build_order(
    const int* __restrict__ coords, unsigned int* __restrict__ order)
{
    __shared__ unsigned short cnt[256][16];   // [chunk][band] 8 KB
    __shared__ unsigned short part[16][17];   // [band][sub]
    __shared__ unsigned int   base[16];

    const int t   = threadIdx.x;
    const int b   = blockIdx.x;
    const int key16 = t >> 4;   // this thread's band for the prefix phases
    const int sub   = t & 15;

    #pragma unroll
    for (int k = 0; k < 16; ++k) cnt[t][k] = 0;
    __syncthreads();

    const int2* c2 = (const int2*)coords;
    unsigned int pk[16];
    #pragma unroll
    for (int i = 0; i < 16; ++i) {
        const int p = (b << 12) + (i << 8) + t;       // coalesced
        const int2 hw = c2[p];
        pk[i] = ((unsigned)b << 18) | ((unsigned)hw.x << 9) | (unsigned)hw.y;
        cnt[t][hw.x >> 5]++;
    }
    __syncthreads();

    // sum this band over 16 chunks (thread = (band, sub))
    unsigned run = 0;
    #pragma unroll
    for (int tt = sub * 16; tt < sub * 16 + 16; ++tt) run += cnt[tt][key16];
    part[key16][sub] = (unsigned short)run;
    __syncthreads();

    // exclusive prefix over subs per band, then over bands
    if (t < 16) {
        unsigned r = 0;
        #pragma unroll
        for (int s = 0; s < 16; ++s) { unsigned v = part[t][s]; part[t][s] = (unsigned short)r; r += v; }
        base[t] = r;
    }
    __syncthreads();
    if (t == 0) {
        unsigned r = 0;
        #pragma unroll
        for (int k = 0; k < 16; ++k) { unsigned v = base[k]; base[k] = r; r += v; }
    }
    __syncthreads();

    // rewrite cnt[tt][band] to exclusive prefix within bucket
    {
        unsigned r = part[key16][sub];
        #pragma unroll
        for (int tt = sub * 16; tt < sub * 16 + 16; ++tt) {
            unsigned v = cnt[tt][key16]; cnt[tt][key16] = (unsigned short)r; r += v;
        }
    }
    __syncthreads();

    // scatter: deterministic unique positions
    #pragma unroll
    for (int i = 0; i < 16; ++i) {
        const unsigned key = (pk[i] >> 14) & 15;      // h >> 5
        const unsigned pos = base[key] + cnt[t][key];
        cnt[t][key]++;
        order[(b << 12) + pos] = pk[i];
    }
}

// ---- kernel 2: per-patch loss, sorted order + XCD-contiguous swizzle ----
__global__ __launch_bounds__(256) void patch_stage1(
    const float* __restrict__ fuse,
    const float* __restrict__ img1,
    const float* __restrict__ img2,
    const unsigned int* __restrict__ order,
    float* __restrict__ partials)
{
    const int lane = threadIdx.x & 63;
    const int wave = threadIdx.x >> 6;
    // bijective XCD swizzle: XCD x (= bid%8) owns contiguous sorted slots
    const int bid     = blockIdx.x;
    const int slotblk = (bid & 7) * (NBLK / 8) + (bid >> 3);
    const int slot    = slotblk * 4 + wave;

    const unsigned v = order[slot];
    const int w = v & 511;
    const int h = (v >> 9) & 511;
    const int b = v >> 18;

    const size_t pbase = ((size_t)(b * CD) * HD + h) * WD + w
                       + (size_t)(lane >> 2) * WD + (size_t)((lane & 3) * 4);

    f4 vf[3], v1[3], v2[3];
    #pragma unroll
    for (int c = 0; c < CD; ++c) {
        const size_t idx = pbase + (size_t)c * PLANE;
        vf[c] = *(const f4*)(fuse + idx);
        v1[c] = *(const f4*)(img1 + idx);
        v2[c] = *(const f4*)(img2 + idx);
    }

    float s1[3], q1[3], s2[3], q2[3];
    #pragma unroll
    for (int c = 0; c < CD; ++c) {
        s1[c] = v1[c].x + v1[c].y + v1[c].z + v1[c].w;
        q1[c] = v1[c].x * v1[c].x + v1[c].y * v1[c].y
              + v1[c].z * v1[c].z + v1[c].w * v1[c].w;
        s2[c] = v2[c].x + v2[c].y + v2[c].z + v2[c].w;
        q2[c] = v2[c].x * v2[c].x + v2[c].y * v2[c].y
              + v2[c].z * v2[c].z + v2[c].w * v2[c].w;
    }

    #pragma unroll
    for (int off = 32; off >= 1; off >>= 1) {
        #pragma unroll
        for (int c = 0; c < CD; ++c) {
            s1[c] += __shfl_xor(s1[c], off, 64);
            q1[c] += __shfl_xor(q1[c], off, 64);
            s2[c] += __shfl_xor(s2[c], off, 64);
            q2[c] += __shfl_xor(q2[c], off, 64);
        }
    }

    float acc = 0.f;
    const float inv = 1.f / 256.f;
    #pragma unroll
    for (int c = 0; c < CD; ++c) {
        const float mu1 = s1[c] * inv;
        const float mu2 = s2[c] * inv;
        const float sd1 = sqrtf(fmaxf(q1[c] * inv - mu1 * mu1, 0.f));
        const float sd2 = sqrtf(fmaxf(q2[c] * inv - mu2 * mu2, 0.f));
        const float denom = sd1 + sd2 + 1e-6f;
        const float w1 = sd1 / denom;
        const float w2 = sd2 / denom;
        acc += fabsf(vf[c].x - (w1 * v1[c].x + w2 * v2[c].x))
             + fabsf(vf[c].y - (w1 * v1[c].y + w2 * v2[c].y))
             + fabsf(vf[c].z - (w1 * v1[c].z + w2 * v2[c].z))
             + fabsf(vf[c].w - (w1 * v1[c].w + w2 * v2[c].w));
    }

    #pragma unroll
    for (int off = 32; off >= 1; off >>= 1)
        acc += __shfl_xor(acc, off, 64);

    __shared__ float partsm[4];
    if (lane == 0) partsm[wave] = acc;
    __syncthreads();
    if (threadIdx.x == 0)
        partials[bid] = partsm[0] + partsm[1] + partsm[2] + partsm[3];
}

// ---- kernel 3: final reduction ----
__global__ __launch_bounds__(256) void patch_stage2(
    const float* __restrict__ partials, float* __restrict__ out)
{
    float s = 0.f;
    for (int i = threadIdx.x; i < NBLK; i += 256)
        s += partials[i];

    #pragma unroll
    for (int off = 32; off >= 1; off >>= 1)
        s += __shfl_xor(s, off, 64);

    __shared__ float partsm[4];
    const int lane = threadIdx.x & 63;
    const int wave = threadIdx.x >> 6;
    if (lane == 0) partsm[wave] = s;
    __syncthreads();
    if (threadIdx.x == 0)
        out[0] = (partsm[0] + partsm[1] + partsm[2] + partsm[3]) * (float)(1.0 / TOTAL_ELEMS);
}

extern "C" void kernel_launch(void* const* d_in, const int* in_sizes, int n_in,
                              void* d_out, int out_size, void* d_ws, size_t ws_size,
                              hipStream_t stream) {
    const float* fuse   = (const float*)d_in[0];
    const float* img1   = (const float*)d_in[1];
    const float* img2   = (const float*)d_in[2];
    const int*   coords = (const int*)d_in[3];
    float* out = (float*)d_out;

    unsigned int* order    = (unsigned int*)d_ws;            // 64 KB
    float*        partials = (float*)((char*)d_ws + NP * 4); // 16 KB

    build_order<<<BD, 256, 0, stream>>>(coords, order);
    patch_stage1<<<NBLK, 256, 0, stream>>>(fuse, img1, img2, order, partials);
    patch_stage2<<<1, 256, 0, stream>>>(partials, out);
}